// Round 8
// baseline (175.659 us; speedup 1.0000x reference)
//
#include <hip/hip_runtime.h>
#include <math.h>

#define NN 1024
#define CC 256
#define TT 64

typedef float __attribute__((ext_vector_type(4))) f32x4;

// ---------------- kernel 1: fused time-mean + row norm ----------------
// Round-7 proven NT version (dropped out of top-5; dist now dominates).
// Block per (tensor,row): 2048 blocks x 256 threads; wave w sums t-steps
// [16w,16w+16), lane owns float4-group lane. Non-temporal loads keep the
// 128MB input out of L3 -> pure-HBM streaming regime.
__global__ __launch_bounds__(256) void mean_norm_kernel(
    const float* __restrict__ in0, const float* __restrict__ in1,
    float* __restrict__ x, float* __restrict__ y,
    float* __restrict__ nx, float* __restrict__ ny) {
  __shared__ f32x4 red[3][64];
  int b = blockIdx.x;
  int m = b >> 10;
  int n = b & (NN - 1);
  const f32x4* src = (const f32x4*)((m ? in1 : in0) + (size_t)n * (TT * CC));
  float* xo = m ? y : x;
  float* no = m ? ny : nx;
  int tid = threadIdx.x;
  int w = tid >> 6;            // wave id = time-quarter
  int lane = tid & 63;
  const f32x4* p0 = src + (size_t)(w * 16) * (CC / 4) + lane;

  f32x4 a0 = (f32x4)0.f;
  f32x4 a1 = (f32x4)0.f;
  #pragma unroll
  for (int i = 0; i < 16; i += 2) {
    a0 += __builtin_nontemporal_load(p0 + (size_t)i * (CC / 4));
    a1 += __builtin_nontemporal_load(p0 + (size_t)(i + 1) * (CC / 4));
  }
  f32x4 s = a0 + a1;
  if (w) red[w - 1][lane] = s;
  __syncthreads();
  if (w == 0) {
    #pragma unroll
    for (int j = 0; j < 3; ++j) s += red[j][lane];
    s *= (1.0f / TT);
    ((f32x4*)(xo + (size_t)n * CC))[lane] = s;
    float ssq = fmaf(s.x, s.x, fmaf(s.y, s.y, fmaf(s.z, s.z, s.w * s.w)));
    #pragma unroll
    for (int o = 32; o > 0; o >>= 1) ssq += __shfl_down(ssq, o, 64);
    if (lane == 0) no[n] = ssq;
  }
}

// ---------------- kernel 2: fused pairwise-distance + reductions ----------------
// INDEPENDENT-BLOCK version. Round-7 counters: 512-thr/128KB dist = 79.5us
// at VALUBusy 14%, occ 22% -> stall-bound (LDS-pipe floor ~24us): all 8
// waves share one barrier domain, so staging + barrier drains idle the
// whole CU. Fix mechanism: tile 32(i)x64(j), grid (16,32)=512 blocks x 256
// threads, 48KB LDS -> TWO co-resident blocks per CU with independent
// barriers; one block computes while the other stages/drains.
// Microtile 2(i)x4(j); K in 4 single-buffered chunks of 16 f4 (64 ch).
// Swizzle pg = g ^ ((r>>2)&7):
//   B-reads (rows 4tx+q): pg = g^(tx&7) -> 8 bank-quads x 2 tx   (free)
//   A-reads (rows 2ty+p): pg = g^((ty>>1)&7), bcast over tx, 2-way (free)
//   staging writes: 4 consecutive rows x 16 g -> 2-way            (free)
__global__ __launch_bounds__(256) void dist_kernel(
    const float* __restrict__ x, const float* __restrict__ y,
    const float* __restrict__ nx, const float* __restrict__ ny,
    float* __restrict__ Rxp, float* __restrict__ Ryp,
    float* __restrict__ pab, float* __restrict__ paa, float* __restrict__ pbb) {
  __shared__ float4 tA[2][32][16];   // [mat X/Y][i-row][g]  16 KB
  __shared__ float4 tB[2][64][16];   // [mat X/Y][j-row][g]  32 KB
  __shared__ float redp[3][4];

  int tid = threadIdx.x;
  int tx = tid & 15, ty = tid >> 4;  // tx -> j, ty -> i
  int bx = blockIdx.x;               // j-tile 0..15
  int by = blockIdx.y;               // i-tile 0..31
  int ti = by * 32, tj = bx * 64;

  float accx[2][4] = {};
  float accy[2][4] = {};

  const float4* gx = (const float4*)x;   // [row][64] float4 groups
  const float4* gy = (const float4*)y;

  for (int kc = 0; kc < 4; ++kc) {   // 4 chunks of 16 f4 (64 channels)
    if (kc) __syncthreads();         // protect LDS from previous compute
    // stage A: 1024 f4 (2 mat x 32 rows x 16 g), 4 per thread
    #pragma unroll
    for (int s2 = 0; s2 < 4; ++s2) {
      int idx = tid + s2 * 256;
      int mt = idx >> 9, rem = idx & 511;
      int r = rem >> 4, g = rem & 15;
      int pg = g ^ ((r >> 2) & 7);
      const float4* src = mt ? gy : gx;
      tA[mt][r][pg] = src[(size_t)(ti + r) * 64 + kc * 16 + g];
    }
    // stage B: 2048 f4 (2 mat x 64 rows x 16 g), 8 per thread
    #pragma unroll
    for (int s2 = 0; s2 < 8; ++s2) {
      int idx = tid + s2 * 256;
      int mt = idx >> 10, rem = idx & 1023;
      int r = rem >> 4, g = rem & 15;
      int pg = g ^ ((r >> 2) & 7);
      const float4* src = mt ? gy : gx;
      tB[mt][r][pg] = src[(size_t)(tj + r) * 64 + kc * 16 + g];
    }
    __syncthreads();
    #pragma unroll
    for (int g = 0; g < 16; ++g) {
      float4 bxv[4], byv[4];
      int pgb = g ^ (tx & 7);
      #pragma unroll
      for (int q = 0; q < 4; ++q) {
        bxv[q] = tB[0][4 * tx + q][pgb];
        byv[q] = tB[1][4 * tx + q][pgb];
      }
      int pga = g ^ ((ty >> 1) & 7);
      #pragma unroll
      for (int p = 0; p < 2; ++p) {
        float4 ax = tA[0][2 * ty + p][pga];
        float4 ay = tA[1][2 * ty + p][pga];
        #pragma unroll
        for (int q = 0; q < 4; ++q) {
          accx[p][q] = fmaf(ax.w, bxv[q].w, fmaf(ax.z, bxv[q].z,
                       fmaf(ax.y, bxv[q].y, fmaf(ax.x, bxv[q].x, accx[p][q]))));
          accy[p][q] = fmaf(ay.w, byv[q].w, fmaf(ay.z, byv[q].z,
                       fmaf(ay.y, byv[q].y, fmaf(ay.x, byv[q].x, accy[p][q]))));
        }
      }
    }
  }

  // epilogue: d = sqrt(max(ni+nj-2g,0)+1e-12); accumulate sums
  float nix[2], niy[2], njx[4], njy[4];
  #pragma unroll
  for (int p = 0; p < 2; ++p) { nix[p] = nx[ti + 2 * ty + p]; niy[p] = ny[ti + 2 * ty + p]; }
  #pragma unroll
  for (int q = 0; q < 4; ++q) { njx[q] = nx[tj + 4 * tx + q]; njy[q] = ny[tj + 4 * tx + q]; }

  float ab = 0.f, aa = 0.f, bb = 0.f;
  #pragma unroll
  for (int p = 0; p < 2; ++p) {
    float rsx = 0.f, rsy = 0.f;
    #pragma unroll
    for (int q = 0; q < 4; ++q) {
      float dxv = sqrtf(fmaxf(nix[p] + njx[q] - 2.f * accx[p][q], 0.f) + 1e-12f);
      float dyv = sqrtf(fmaxf(niy[p] + njy[q] - 2.f * accy[p][q], 0.f) + 1e-12f);
      ab = fmaf(dxv, dyv, ab);
      aa = fmaf(dxv, dxv, aa);
      bb = fmaf(dyv, dyv, bb);
      rsx += dxv; rsy += dyv;
    }
    // reduce row partial over the 16 tx-lanes of this ty-group
    #pragma unroll
    for (int o = 8; o > 0; o >>= 1) {
      rsx += __shfl_down(rsx, o, 16);
      rsy += __shfl_down(rsy, o, 16);
    }
    if (tx == 0) {
      Rxp[bx * NN + ti + 2 * ty + p] = rsx;
      Ryp[bx * NN + ti + 2 * ty + p] = rsy;
    }
  }

  // block-level product partials over 4 waves
  #pragma unroll
  for (int o = 32; o > 0; o >>= 1) {
    ab += __shfl_down(ab, o, 64);
    aa += __shfl_down(aa, o, 64);
    bb += __shfl_down(bb, o, 64);
  }
  int wv = tid >> 6;
  if ((tid & 63) == 0) { redp[0][wv] = ab; redp[1][wv] = aa; redp[2][wv] = bb; }
  __syncthreads();
  if (tid == 0) {
    int blk = by * 16 + bx;            // 0..511
    pab[blk] = redp[0][0] + redp[0][1] + redp[0][2] + redp[0][3];
    paa[blk] = redp[1][0] + redp[1][1] + redp[1][2] + redp[1][3];
    pbb[blk] = redp[2][0] + redp[2][1] + redp[2][2] + redp[2][3];
  }
}

// ---------------- kernel 3: finalize ----------------
// <A,B> = S(DxDy) - (2/n) S(Rx.Ry) + Sx.Sy/n^2  (H idempotent, D symmetric)
// pab/paa/pbb now hold 512 block partials (i-split dist) -> 2 per thread.
__global__ __launch_bounds__(256) void finalize_kernel(
    const float* __restrict__ Rxp, const float* __restrict__ Ryp,
    const float* __restrict__ pab, const float* __restrict__ paa,
    const float* __restrict__ pbb, float* __restrict__ out) {
  int tid = threadIdx.x;
  const float4* rx4 = (const float4*)Rxp;
  const float4* ry4 = (const float4*)Ryp;
  float4 Rx = make_float4(0.f, 0.f, 0.f, 0.f);
  float4 Ry = make_float4(0.f, 0.f, 0.f, 0.f);
  #pragma unroll
  for (int b = 0; b < 16; ++b) {
    float4 v = rx4[b * 256 + tid];
    Rx.x += v.x; Rx.y += v.y; Rx.z += v.z; Rx.w += v.w;
    float4 w = ry4[b * 256 + tid];
    Ry.x += w.x; Ry.y += w.y; Ry.z += w.z; Ry.w += w.w;
  }
  double sx = (double)Rx.x + Rx.y + Rx.z + Rx.w;
  double sy = (double)Ry.x + Ry.y + Ry.z + Ry.w;
  double srr = (double)Rx.x * Ry.x + (double)Rx.y * Ry.y + (double)Rx.z * Ry.z + (double)Rx.w * Ry.w;
  double sxx = (double)Rx.x * Rx.x + (double)Rx.y * Rx.y + (double)Rx.z * Rx.z + (double)Rx.w * Rx.w;
  double syy = (double)Ry.x * Ry.x + (double)Ry.y * Ry.y + (double)Ry.z * Ry.z + (double)Ry.w * Ry.w;
  double ab = (double)pab[tid] + (double)pab[tid + 256];
  double aa = (double)paa[tid] + (double)paa[tid + 256];
  double bb = (double)pbb[tid] + (double)pbb[tid + 256];
  #pragma unroll
  for (int o = 32; o > 0; o >>= 1) {
    sx += __shfl_down(sx, o, 64);  sy += __shfl_down(sy, o, 64);
    srr += __shfl_down(srr, o, 64); sxx += __shfl_down(sxx, o, 64);
    syy += __shfl_down(syy, o, 64); ab += __shfl_down(ab, o, 64);
    aa += __shfl_down(aa, o, 64);  bb += __shfl_down(bb, o, 64);
  }
  __shared__ double t[8][4];
  int lane = tid & 63, w = tid >> 6;
  if (lane == 0) {
    t[0][w] = sx; t[1][w] = sy; t[2][w] = srr; t[3][w] = sxx;
    t[4][w] = syy; t[5][w] = ab; t[6][w] = aa; t[7][w] = bb;
  }
  __syncthreads();
  if (tid == 0) {
    sx  = t[0][0] + t[0][1] + t[0][2] + t[0][3];
    sy  = t[1][0] + t[1][1] + t[1][2] + t[1][3];
    srr = t[2][0] + t[2][1] + t[2][2] + t[2][3];
    sxx = t[3][0] + t[3][1] + t[3][2] + t[3][3];
    syy = t[4][0] + t[4][1] + t[4][2] + t[4][3];
    ab  = t[5][0] + t[5][1] + t[5][2] + t[5][3];
    aa  = t[6][0] + t[6][1] + t[6][2] + t[6][3];
    bb  = t[7][0] + t[7][1] + t[7][2] + t[7][3];
    const double n = (double)NN, n2 = n * n;
    double AB = ab - (2.0 / n) * srr + sx * sy / n2;
    double AA = aa - (2.0 / n) * sxx + sx * sx / n2;
    double BB = bb - (2.0 / n) * syy + sy * sy / n2;
    double xy = AB / n2, xx = AA / n2, yy = BB / n2;
    double r = xy / sqrt(xx * yy + 1e-9);
    out[0] = (float)(1.0 - r);
  }
}

extern "C" void kernel_launch(void* const* d_in, const int* in_sizes, int n_in,
                              void* d_out, int out_size, void* d_ws, size_t ws_size,
                              hipStream_t stream) {
  const float* in0 = (const float*)d_in[0];   // output_1 (N,T,C) fp32
  const float* in1 = (const float*)d_in[1];   // feature  (N,T,C) fp32

  char* ws = (char*)d_ws;
  float* x   = (float*)(ws);                          // 1 MB
  float* y   = (float*)(ws + (1u << 20));             // 1 MB
  float* nx  = (float*)(ws + (2u << 20));             // 4 KB
  float* ny  = (float*)(ws + (2u << 20) + 4096);      // 4 KB
  float* Rxp = (float*)(ws + (2u << 20) + 8192);      // 64 KB (16x1024)
  float* Ryp = (float*)(ws + (2u << 20) + 8192 + 65536);        // 64 KB
  float* pab = (float*)(ws + (2u << 20) + 8192 + 2 * 65536);    // 2 KB (512)
  float* paa = (float*)(ws + (2u << 20) + 8192 + 2 * 65536 + 2048);
  float* pbb = (float*)(ws + (2u << 20) + 8192 + 2 * 65536 + 4096);

  mean_norm_kernel<<<2 * NN, 256, 0, stream>>>(in0, in1, x, y, nx, ny);
  dist_kernel<<<dim3(16, 32), 256, 0, stream>>>(x, y, nx, ny, Rxp, Ryp, pab, paa, pbb);
  finalize_kernel<<<1, 256, 0, stream>>>(Rxp, Ryp, pab, paa, pbb, (float*)d_out);
}